// Round 2
// baseline (1979.843 us; speedup 1.0000x reference)
//
#include <hip/hip_runtime.h>
#include <stdint.h>

#define NEG_SLOPE 0.01f
#define EPSF 1e-10f

__device__ __forceinline__ float lrelu(float x){
  return fmaxf(x, 0.f) + NEG_SLOPE * fminf(x, 0.f);
}

// K0: repack W [2][64][32] fp32 -> Wf [64 k][64 j] (j = c*32+jj), b -> bf[64]
__global__ void conv_wb(const float* __restrict__ W,
                        const float* __restrict__ b,
                        float* __restrict__ Wf, float* __restrict__ bf){
  int i = blockIdx.x * blockDim.x + threadIdx.x;
  for (int idx = i; idx < 64 * 64; idx += blockDim.x * gridDim.x){
    int k = idx >> 6, j = idx & 63;
    int c = j >> 5, jj = j & 31;
    Wf[idx] = W[c * 2048 + k * 32 + jj];
  }
  if (i < 64) bf[i] = b[i];   // b flat [2][1][32] already matches j = c*32+jj
}

// K1: projection. One thread per node: h[n][j] = leaky(sum_k ego[n][k]*Wf[k][j] + bf[j])
__global__ __launch_bounds__(256) void proj(const float* __restrict__ ego,
                                            const float* __restrict__ Wf,
                                            const float* __restrict__ bf,
                                            float* __restrict__ h, int N){
  int n = blockIdx.x * 256 + threadIdx.x;
  if (n >= N) return;
  float acc[64];
  #pragma unroll
  for (int j = 0; j < 64; j++) acc[j] = bf[j];
  const float4* ep = (const float4*)(ego + (size_t)n * 64);
  for (int kk = 0; kk < 16; kk++){
    float4 q = ep[kk];
    float ev[4] = {q.x, q.y, q.z, q.w};
    const float* wbase = Wf + kk * 4 * 64;   // uniform address -> s_load expected
    #pragma unroll
    for (int t = 0; t < 4; t++){
      float ek = ev[t];
      const float* wrow = wbase + t * 64;
      #pragma unroll
      for (int j = 0; j < 64; j++) acc[j] = fmaf(ek, wrow[j], acc[j]);
    }
  }
  float4* hp = (float4*)(h + (size_t)n * 64);
  #pragma unroll
  for (int v = 0; v < 16; v++){
    float4 o;
    o.x = lrelu(acc[4 * v + 0]);
    o.y = lrelu(acc[4 * v + 1]);
    o.z = lrelu(acc[4 * v + 2]);
    o.w = lrelu(acc[4 * v + 3]);
    hp[v] = o;
  }
}

// K2: histogram of destination rows
__global__ void hist_k(const int* __restrict__ row, int* __restrict__ deg, int E){
  int i = blockIdx.x * blockDim.x + threadIdx.x;
  int stride = blockDim.x * gridDim.x;
  for (; i < E; i += stride) atomicAdd(&deg[row[i]], 1);
}

// K3a: per-chunk (1024 elems) sums
__global__ __launch_bounds__(256) void scanA(const int* __restrict__ deg,
                                             int* __restrict__ bsum, int N){
  __shared__ int sh[256];
  int t = threadIdx.x;
  int base = blockIdx.x * 1024;
  int s = 0;
  #pragma unroll
  for (int i = 0; i < 4; i++){
    int idx = base + i * 256 + t;
    if (idx < N) s += deg[idx];
  }
  sh[t] = s; __syncthreads();
  for (int off = 128; off > 0; off >>= 1){
    if (t < off) sh[t] += sh[t + off];
    __syncthreads();
  }
  if (t == 0) bsum[blockIdx.x] = sh[0];
}

// K3b: exclusive scan of chunk sums (<=1024 chunks)
__global__ __launch_bounds__(1024) void scanB(const int* __restrict__ bsum,
                                              int* __restrict__ bbase, int nb){
  __shared__ int sh[1024];
  int t = threadIdx.x;
  int v = (t < nb) ? bsum[t] : 0;
  sh[t] = v; __syncthreads();
  for (int off = 1; off < 1024; off <<= 1){
    int add = (t >= off) ? sh[t - off] : 0;
    __syncthreads();
    sh[t] += add;
    __syncthreads();
  }
  if (t < nb) bbase[t] = sh[t] - v;
}

// K3c: full exclusive scan -> offsets, and cursor copy
__global__ __launch_bounds__(256) void scanC(const int* __restrict__ deg,
                                             const int* __restrict__ bbase,
                                             int* __restrict__ offs,
                                             int* __restrict__ cur, int N){
  __shared__ int sh[256];
  int t = threadIdx.x;
  int base = blockIdx.x * 1024 + t * 4;
  int d[4];
  #pragma unroll
  for (int i = 0; i < 4; i++){
    int idx = base + i;
    d[i] = (idx < N) ? deg[idx] : 0;
  }
  int s = d[0] + d[1] + d[2] + d[3];
  sh[t] = s; __syncthreads();
  for (int off = 1; off < 256; off <<= 1){
    int add = (t >= off) ? sh[t - off] : 0;
    __syncthreads();
    sh[t] += add;
    __syncthreads();
  }
  int o = bbase[blockIdx.x] + (sh[t] - s);
  #pragma unroll
  for (int i = 0; i < 4; i++){
    int idx = base + i;
    if (idx < N){ offs[idx] = o; cur[idx] = o; }
    o += d[i];
  }
}

// K4: scatter col indices into row-sorted order
__global__ void scatter_k(const int* __restrict__ row, const int* __restrict__ col,
                          int* __restrict__ cur, int* __restrict__ colp, int E){
  int i = blockIdx.x * blockDim.x + threadIdx.x;
  int stride = blockDim.x * gridDim.x;
  for (; i < E; i += stride){
    int r = row[i];
    int pos = atomicAdd(&cur[r], 1);
    colp[pos] = col[i];
  }
}

// K5: fused per-(node, channel) attention aggregation
__global__ __launch_bounds__(256) void agg(const float* __restrict__ h,
                                           const int* __restrict__ offs,
                                           const int* __restrict__ deg,
                                           const int* __restrict__ colp,
                                           float* __restrict__ out, int N){
  int n = blockIdx.x * 256 + threadIdx.x;
  int ch = blockIdx.y;
  if (n >= N) return;
  const float4* hr4 = (const float4*)(h + (size_t)n * 64 + ch * 32);
  float hr[32];
  #pragma unroll
  for (int v = 0; v < 8; v++){
    float4 q = hr4[v];
    hr[4 * v + 0] = q.x; hr[4 * v + 1] = q.y; hr[4 * v + 2] = q.z; hr[4 * v + 3] = q.w;
  }
  float acc[32];
  #pragma unroll
  for (int j = 0; j < 32; j++) acc[j] = 0.f;
  float l = 0.f;
  int s = offs[n], d = deg[n];
  for (int p = s; p < s + d; ++p){
    int c = colp[p];
    const float4* hc4 = (const float4*)(h + (size_t)c * 64 + ch * 32);
    float hc[32];
    #pragma unroll
    for (int v = 0; v < 8; v++){
      float4 q = hc4[v];
      hc[4 * v + 0] = q.x; hc[4 * v + 1] = q.y; hc[4 * v + 2] = q.z; hc[4 * v + 3] = q.w;
    }
    float dot = 0.f;
    #pragma unroll
    for (int j = 0; j < 32; j++) dot = fmaf(hr[j], hc[j], dot);
    float lg = fminf(lrelu(dot), 80.f);
    float w = __expf(lg);
    l += w;
    #pragma unroll
    for (int j = 0; j < 32; j++) acc[j] = fmaf(w, hc[j], acc[j]);
  }
  float inv = 1.f / (l + EPSF);
  float4* op = (float4*)(out + (size_t)n * 64 + ch * 32);
  #pragma unroll
  for (int v = 0; v < 8; v++){
    float4 o;
    o.x = acc[4 * v + 0] * inv;
    o.y = acc[4 * v + 1] * inv;
    o.z = acc[4 * v + 2] * inv;
    o.w = acc[4 * v + 3] * inv;
    op[v] = o;
  }
}

extern "C" void kernel_launch(void* const* d_in, const int* in_sizes, int n_in,
                              void* d_out, int out_size, void* d_ws, size_t ws_size,
                              hipStream_t stream){
  const float* ego = (const float*)d_in[0];
  const float* W   = (const float*)d_in[1];
  const float* b   = (const float*)d_in[2];
  const int* row = (const int*)d_in[3];
  const int* col = (const int*)d_in[4];
  int N = in_sizes[0] / 64;
  int E = in_sizes[3];
  float* out = (float*)d_out;

  char* ws = (char*)d_ws;
  float* Wf = (float*)ws;                       // 4096 f
  float* bf = Wf + 4096;                        // 64 f
  float* h  = (float*)(ws + 32768);             // N*64 fp32
  size_t hbytes = (size_t)N * 64 * 4;
  int* deg   = (int*)(ws + 32768 + hbytes);     // N
  int* offs  = deg + N;                         // N
  int* cur   = offs + N;                        // N
  int* bsum  = cur + N;                         // 2048
  int* bbase = bsum + 2048;                     // 2048
  int* colp  = bbase + 2048;                    // E

  int nChunks = (N + 1023) / 1024;

  hipMemsetAsync(deg, 0, (size_t)N * 4, stream);
  conv_wb<<<16, 256, 0, stream>>>(W, b, Wf, bf);
  proj<<<(N + 255) / 256, 256, 0, stream>>>(ego, Wf, bf, h, N);
  hist_k<<<2048, 256, 0, stream>>>(row, deg, E);
  scanA<<<nChunks, 256, 0, stream>>>(deg, bsum, N);
  scanB<<<1, 1024, 0, stream>>>(bsum, bbase, nChunks);
  scanC<<<nChunks, 256, 0, stream>>>(deg, bbase, offs, cur, N);
  scatter_k<<<2048, 256, 0, stream>>>(row, col, cur, colp, E);
  dim3 g((N + 255) / 256, 2);
  agg<<<g, 256, 0, stream>>>(h, offs, deg, colp, out, N);
}